// Round 7
// baseline (90.403 us; speedup 1.0000x reference)
//
#include <hip/hip_runtime.h>
#include <math.h>

#define NUM_EMB 512
#define DIMV 65          // 65
#define DD   64          // DIM-1
#define BB   2048
#define NN   256

typedef short short8 __attribute__((ext_vector_type(8)));   // 8 bf16 (4 VGPR)
typedef float f32x4  __attribute__((ext_vector_type(4)));   // MFMA acc

__device__ __forceinline__ float gelu_exact(float x) {
    return 0.5f * x * (1.0f + erff(x * 0.7071067811865475f));
}

// fp32 -> bf16, round-to-nearest-even, deterministic
__device__ __forceinline__ unsigned short f2bf(float f) {
    unsigned u = __builtin_bit_cast(unsigned, f);
    u += 0x7FFFu + ((u >> 16) & 1u);
    return (unsigned short)(u >> 16);
}

// ---------------------------------------------------------------------------
// Kernel 1: build W[e] = H0 @ ... @ H63 (Householder matvec + rank-1 update),
// scale last column, store TRANSPOSED bf16: WgT[e][c][d] = bf16(W[e][d][c]).
// ---------------------------------------------------------------------------
__global__ __launch_bounds__(256) void build_W(const float* __restrict__ emb,
                                               const float* __restrict__ flip_sign,
                                               const int*   __restrict__ r_idx,
                                               unsigned short* __restrict__ WgT,
                                               float* __restrict__ out) {
    __shared__ float v_lds[DD * DD];
    __shared__ float s_lds[DD];
    const int e = blockIdx.x;
    const int t = threadIdx.x;
    const int r = t >> 2;
    const int q = t & 3;

    const float* erow = emb + (size_t)e * (DD * DD);
    #pragma unroll
    for (int p = 0; p < 16; ++p) {
        int idx = p * 256 + t;
        v_lds[idx] = gelu_exact(erow[idx]);
    }

    // r_idx passthrough: output 1 lives at out[BB*NN*DIMV + b]
    if (t < 4) {
        int bi = e * 4 + t;
        out[(size_t)BB * NN * DIMV + bi] = (float)r_idx[bi];
    }
    __syncthreads();

    {
        const float* vr = &v_lds[r * DD + q * 16];
        float ss = 0.f;
        #pragma unroll
        for (int k = 0; k < 16; ++k) ss += vr[k] * vr[k];
        ss += __shfl_xor(ss, 1);
        ss += __shfl_xor(ss, 2);
        if (q == 0) s_lds[r] = 2.0f / ss;
    }
    __syncthreads();

    float Wq[16];
    #pragma unroll
    for (int k = 0; k < 16; ++k) Wq[k] = ((q * 16 + k) == r) ? 1.0f : 0.0f;

    // prefetch vv for w=0
    float vv[16], nv[16];
    {
        const float* vr = &v_lds[q * 16];
        *(float4*)&nv[0]  = *(const float4*)&vr[0];
        *(float4*)&nv[4]  = *(const float4*)&vr[4];
        *(float4*)&nv[8]  = *(const float4*)&vr[8];
        *(float4*)&nv[12] = *(const float4*)&vr[12];
    }

    for (int w = 0; w < DD; ++w) {
        #pragma unroll
        for (int k = 0; k < 16; ++k) vv[k] = nv[k];
        if (w < DD - 1) {
            const float* vr = &v_lds[(w + 1) * DD + q * 16];
            *(float4*)&nv[0]  = *(const float4*)&vr[0];
            *(float4*)&nv[4]  = *(const float4*)&vr[4];
            *(float4*)&nv[8]  = *(const float4*)&vr[8];
            *(float4*)&nv[12] = *(const float4*)&vr[12];
        }
        float p0 = Wq[0] * vv[0],  p1 = Wq[1] * vv[1];
        float p2 = Wq[2] * vv[2],  p3 = Wq[3] * vv[3];
        #pragma unroll
        for (int k = 4; k < 16; k += 4) {
            p0 += Wq[k]     * vv[k];
            p1 += Wq[k + 1] * vv[k + 1];
            p2 += Wq[k + 2] * vv[k + 2];
            p3 += Wq[k + 3] * vv[k + 3];
        }
        float p = (p0 + p1) + (p2 + p3);
        p += __shfl_xor(p, 1);
        p += __shfl_xor(p, 2);
        const float sc = s_lds[w] * p;
        #pragma unroll
        for (int k = 0; k < 16; ++k) Wq[k] -= sc * vv[k];
    }

    if (q == 3) Wq[15] *= flip_sign[0];

    // store transposed bf16: WgT[e][c][d] with c = 16q+k, d = r
    unsigned short* wd = WgT + (size_t)e * (DD * DD) + r;
    #pragma unroll
    for (int k = 0; k < 16; ++k)
        wd[(16 * q + k) * DD] = f2bf(Wq[k]);
}

// ---------------------------------------------------------------------------
// Kernel 2 (MFMA): out[.,0]=x[.,0]; out[.,1+c] = sum_d x[.,1+d]*W[d][c].
// Block = 256 threads (4 waves), 128-row tile of one b. bf16 operands.
// R7 change: staging split into ISSUE-ALL-LOADS (va[32]/vb[8] register
// buffers -> 32 outstanding global loads per thread, ~MLP x4) then
// CONVERT+LDS-WRITE. VGPR rises to ~90 (5 waves/SIMD), LDS caps 6 blk/CU.
//  - A in LDS: As[row][64 k] bf16, XOR-swizzled (byte ^= (row&7)<<4).
//  - B in LDS: Bs[col][64 k] bf16 (prebuilt bf16 W^T), same swizzle.
//  - Wave w: rows [32w,32w+32) x 64 cols: 12 ds_read_b128 + 16 MFMA.
//  - C/D layout (HW-verified): col = lane&15, row = (lane>>4)*4 + reg.
// ---------------------------------------------------------------------------
__global__ __launch_bounds__(256, 2) void apply_W(const float* __restrict__ x,
                                                  const int*   __restrict__ r_idx,
                                                  const unsigned short* __restrict__ WgT,
                                                  float* __restrict__ out) {
    __shared__ alignas(16) unsigned char ldsA[128 * 128];   // 16384 B: A tile
    __shared__ alignas(16) unsigned char ldsB[64 * 128];    //  8192 B: B tile
    const int blk  = blockIdx.x;
    const int b    = blk >> 1;
    const int half = blk & 1;
    const size_t rowbase = (size_t)b * NN + half * 128;
    const int t = threadIdx.x;

    const int e = r_idx[b];   // uniform

    const float* xb = x + rowbase * DIMV;
    const int lane = t & 63;
    const int wv   = t >> 6;

    // ---- phase 1: ISSUE all staging loads into register buffers ----
    float    va[32];                    // x: rows wv+4k, col 1+lane
    #pragma unroll
    for (int k = 0; k < 32; ++k)
        va[k] = xb[(wv + 4 * k) * DIMV + 1 + lane];

    unsigned vb[8];                     // W^T: 2048 dwords
    {
        const unsigned* src = (const unsigned*)(WgT + (size_t)e * (DD * DD));
        #pragma unroll
        for (int p = 0; p < 8; ++p) vb[p] = src[p * 256 + t];
    }

    float x0v[2];                       // col-0 passthrough, rows t, t+... (t<128: row t)
    if (t < 128) x0v[0] = xb[t * DIMV];

    // ---- phase 2: convert + LDS writes (loads drain in order) ----
    #pragma unroll
    for (int p = 0; p < 8; ++p) {
        int i = p * 256 + t;                 // dword index
        int c = i >> 5;                      // B row (W column)
        int off = (i & 31) * 4;              // byte offset within row
        *(unsigned*)&ldsB[c * 128 + (off ^ ((c & 7) << 4))] = vb[p];
    }
    #pragma unroll
    for (int k = 0; k < 32; ++k) {
        int row = wv + 4 * k;
        int off = (lane * 2) ^ ((row & 7) << 4);
        *(unsigned short*)&ldsA[row * 128 + off] = f2bf(va[k]);
    }
    if (t < 128) out[(rowbase + t) * DIMV] = x0v[0];
    __syncthreads();

    const int w     = t >> 6;     // wave 0..3: rows [32w, 32w+32)
    const int l     = t & 63;
    const int lrow  = l & 15;     // fragment M/N index
    const int kslot = l >> 4;     // fragment K group (8 bf16 each)
    const int r0    = w * 32;

    // A fragments: [row-tile][k-block]
    short8 afrg[2][2];
    #pragma unroll
    for (int rt = 0; rt < 2; ++rt)
        #pragma unroll
        for (int kb = 0; kb < 2; ++kb) {
            int row = r0 + rt * 16 + lrow;
            int off = ((kb << 6) | (kslot << 4)) ^ ((row & 7) << 4);
            afrg[rt][kb] = *(const short8*)&ldsA[row * 128 + off];
        }
    // B fragments: [col-tile][k-block]
    short8 bfrg[4][2];
    #pragma unroll
    for (int ct = 0; ct < 4; ++ct)
        #pragma unroll
        for (int kb = 0; kb < 2; ++kb) {
            int col = ct * 16 + lrow;
            int off = ((kb << 6) | (kslot << 4)) ^ ((col & 7) << 4);
            bfrg[ct][kb] = *(const short8*)&ldsB[col * 128 + off];
        }

    // 16 MFMAs, independent accumulators
    f32x4 acc[2][4];
    #pragma unroll
    for (int rt = 0; rt < 2; ++rt)
        #pragma unroll
        for (int ct = 0; ct < 4; ++ct) {
            f32x4 c0 = {0.f, 0.f, 0.f, 0.f};
            c0 = __builtin_amdgcn_mfma_f32_16x16x32_bf16(afrg[rt][0], bfrg[ct][0], c0, 0, 0, 0);
            c0 = __builtin_amdgcn_mfma_f32_16x16x32_bf16(afrg[rt][1], bfrg[ct][1], c0, 0, 0, 0);
            acc[rt][ct] = c0;
        }

    // store: C/D layout col=lane&15, row=(lane>>4)*4+reg
    #pragma unroll
    for (int rt = 0; rt < 2; ++rt) {
        const size_t rowb = rowbase + r0 + rt * 16 + kslot * 4;
        #pragma unroll
        for (int ct = 0; ct < 4; ++ct) {
            #pragma unroll
            for (int rg = 0; rg < 4; ++rg) {
                out[(rowb + rg) * DIMV + 1 + ct * 16 + lrow] = acc[rt][ct][rg];
            }
        }
    }
}

extern "C" void kernel_launch(void* const* d_in, const int* in_sizes, int n_in,
                              void* d_out, int out_size, void* d_ws, size_t ws_size,
                              hipStream_t stream) {
    const float* x         = (const float*)d_in[0];
    const int*   r_idx     = (const int*)d_in[1];
    const float* emb       = (const float*)d_in[2];
    const float* flip_sign = (const float*)d_in[3];
    float* out = (float*)d_out;
    unsigned short* WgT = (unsigned short*)d_ws;   // 512*64*64*2 = 4 MB bf16 W^T

    build_W<<<NUM_EMB, 256, 0, stream>>>(emb, flip_sign, r_idx, WgT, out);
    apply_W<<<BB * 2, 256, 0, stream>>>(x, r_idx, WgT, out);
}